// Round 8
// baseline (432.288 us; speedup 1.0000x reference)
//
#include <hip/hip_runtime.h>
#include <stdint.h>

typedef int i32x4 __attribute__((ext_vector_type(4)));

#define K_DIM 1024
#define BM 256
#define BN 256
#define BKK 64
#define NKT (K_DIM / BKK)   // 16

// Fragment-ordered int8 operand layout (producers aquant/wquant <-> consumer GEMM):
// fragment (F = row/16, T = k/64) is 1KB at offset ((F*16)+T)*1024; byte b
// (l=b>>4, j=b&15) holds value[row=F*16+(l&15)][k=T*64+(l>>4)*16+j].
// -> gld_lds reads are 1KB fully contiguous; LDS image is lane-linear.

// ---------------- helpers ----------------
__device__ __forceinline__ int quant1(float v, float inv) {
  float t = rintf(v * inv);                 // round half-to-even, matches jnp.round
  t = fminf(fmaxf(t, -128.0f), 127.0f);     // clip(-n-1, n)
  return (int)t;
}

__device__ __forceinline__ void gld_lds16(const signed char* g, signed char* l) {
  typedef const __attribute__((address_space(1))) unsigned int* gp_t;
  typedef __attribute__((address_space(3))) unsigned int* lp_t;
  __builtin_amdgcn_global_load_lds((gp_t)(const void*)g, (lp_t)(void*)l, 16, 0, 0);
}

__device__ __forceinline__ void issue_tile(const signed char* gaf, const signed char* gbf,
                                           signed char* Abase, signed char* Bbase,
                                           int wid, int t, size_t fs8) {
  const int b_ = t & 3;
  const size_t kof_ = (size_t)t << 10;
  gld_lds16(gaf + kof_,       Abase + ((b_ * 16 + wid) << 10));
  gld_lds16(gaf + fs8 + kof_, Abase + ((b_ * 16 + wid + 8) << 10));
  gld_lds16(gbf + kof_,       Bbase + ((b_ * 16 + wid) << 10));
  gld_lds16(gbf + fs8 + kof_, Bbase + ((b_ * 16 + wid + 8) << 10));
}

#define SB __builtin_amdgcn_sched_barrier(0)
#define BAR __builtin_amdgcn_s_barrier()
#define WAIT_LGKM0 asm volatile("s_waitcnt lgkmcnt(0)" ::: "memory")

// ---------------- 1a) absmax partials (no atomics, no memset needed) ----------------
__global__ void absmax_part(const float* __restrict__ x, float* __restrict__ parts,
                            long long n4) {
  long long i = (long long)blockIdx.x * blockDim.x + threadIdx.x;
  const long long stride = (long long)gridDim.x * blockDim.x;
  const float4* x4 = (const float4*)x;
  float m = 0.0f;
  for (; i < n4; i += stride) {
    float4 v = x4[i];
    m = fmaxf(m, fmaxf(fmaxf(fabsf(v.x), fabsf(v.y)), fmaxf(fabsf(v.z), fabsf(v.w))));
  }
#pragma unroll
  for (int off = 32; off > 0; off >>= 1) m = fmaxf(m, __shfl_down(m, off, 64));
  __shared__ float sm[4];
  const int lane = threadIdx.x & 63, wid = threadIdx.x >> 6;
  if (lane == 0) sm[wid] = m;
  __syncthreads();
  if (threadIdx.x == 0)
    parts[blockIdx.x] = fmaxf(fmaxf(sm[0], sm[1]), fmaxf(sm[2], sm[3]));
}

// ---------------- 1b) absmax final reduce ----------------
__global__ void absmax_fin(const float* __restrict__ parts, unsigned int* __restrict__ amax_u,
                           int nparts) {
  const int t = threadIdx.x;
  float m = 0.0f;
  for (int i = t; i < nparts; i += 256) m = fmaxf(m, parts[i]);
#pragma unroll
  for (int off = 32; off > 0; off >>= 1) m = fmaxf(m, __shfl_down(m, off, 64));
  __shared__ float sm[4];
  const int lane = t & 63, wid = t >> 6;
  if (lane == 0) sm[wid] = m;
  __syncthreads();
  if (t == 0)
    amax_u[0] = __float_as_uint(fmaxf(fmaxf(sm[0], sm[1]), fmaxf(sm[2], sm[3])));
}

// ---------------- 2) per-channel weight quant + bias (frag-ordered wq) ----------------
__global__ void wquant_kernel(const float* __restrict__ w, const float* __restrict__ bias,
                              const unsigned int* __restrict__ amax_u,
                              signed char* __restrict__ wq,
                              float* __restrict__ bscale, float* __restrict__ bint) {
  const int o = blockIdx.x;
  const int t = threadIdx.x;          // handles k = 4t .. 4t+3
  float4 v = ((const float4*)(w + (size_t)o * K_DIM))[t];
  float m = fmaxf(fmaxf(fabsf(v.x), fabsf(v.y)), fmaxf(fabsf(v.z), fabsf(v.w)));
#pragma unroll
  for (int off = 32; off > 0; off >>= 1) m = fmaxf(m, __shfl_down(m, off, 64));
  __shared__ float sm[4];
  __shared__ float s_scale;
  const int lane = t & 63, wid = t >> 6;
  if (lane == 0) sm[wid] = m;
  __syncthreads();
  if (t == 0) {
    float wm = fmaxf(fmaxf(sm[0], sm[1]), fmaxf(sm[2], sm[3]));
    float wsc = fmaxf(wm, 1e-8f) / 127.0f;
    float asc = fmaxf(__uint_as_float(*amax_u), 1e-8f) / 127.0f;
    float bsc = wsc * asc;
    bscale[o] = bsc;
    bint[o] = rintf(bias[o] / bsc);
    s_scale = wsc;
  }
  __syncthreads();
  const float inv = 1.0f / s_scale;
  int q0 = quant1(v.x, inv), q1 = quant1(v.y, inv), q2 = quant1(v.z, inv), q3 = quant1(v.w, inv);
  unsigned int p = (unsigned)(q0 & 255) | ((unsigned)(q1 & 255) << 8) |
                   ((unsigned)(q2 & 255) << 16) | ((unsigned)(q3 & 255) << 24);
  const int F = o >> 4, T = t >> 4;
  const int l = (((t >> 2) & 3) << 4) | (o & 15);
  const int j = (t << 2) & 15;
  *(unsigned int*)(wq + (((size_t)F << 14) + (T << 10) + (l << 4) + j)) = p;
}

// ---------------- 3) activation quant (frag-ordered xq) ----------------
__global__ void aquant_kernel(const float* __restrict__ x, const unsigned int* __restrict__ amax_u,
                              uint4* __restrict__ q16, int nchunk) {
  const float asc = fmaxf(__uint_as_float(*amax_u), 1e-8f) / 127.0f;
  const float inv = 1.0f / asc;
  int c = blockIdx.x * blockDim.x + threadIdx.x;
  const int stride = gridDim.x * blockDim.x;
  for (; c < nchunk; c += stride) {
    const int l = c & 63, T = (c >> 6) & 15, F = c >> 10;
    const size_t src = (((size_t)(F << 4) + (l & 15)) << 10) + (T << 6) + ((l >> 4) << 4);
    const float4* s4 = (const float4*)(x + src);
    unsigned int r[4];
#pragma unroll
    for (int q = 0; q < 4; q++) {
      float4 v = s4[q];
      int q0 = quant1(v.x, inv), q1 = quant1(v.y, inv), q2 = quant1(v.z, inv), q3 = quant1(v.w, inv);
      r[q] = (unsigned)(q0 & 255) | ((unsigned)(q1 & 255) << 8) |
             ((unsigned)(q2 & 255) << 16) | ((unsigned)(q3 & 255) << 24);
    }
    q16[c] = make_uint4(r[0], r[1], r[2], r[3]);
  }
}

// ---------------- PROBE A: staging-only x5 (ablation) ----------------
// Exact staging pipeline of the GEMM (gld_lds + counted vmcnt + 1 barrier/tile),
// no ds_read/MFMA. Dispatch duration / 5 = per-sweep staging cost.
__global__ __launch_bounds__(512, 2) void probe_stage(
    const signed char* __restrict__ A, const signed char* __restrict__ W,
    signed char* __restrict__ junk, int N) {
  extern __shared__ __align__(16) signed char smem[];
  signed char* Abase = smem;
  signed char* Bbase = smem + 65536;
  const int nwg = gridDim.x;
  const int orig = blockIdx.x;
  const int wgid = (orig & 7) * (nwg >> 3) + (orig >> 3);
  const int nbn = N / BN;
  const int m0 = (wgid / nbn) * BM, n0 = (wgid % nbn) * BN;
  const int tid = threadIdx.x;
  const int lane = tid & 63;
  const int wid = tid >> 6;
  const signed char* gaf = A + (((size_t)(m0 >> 4) + wid) << 14) + (lane << 4);
  const signed char* gbf = W + (((size_t)(n0 >> 4) + wid) << 14) + (lane << 4);
  const size_t fs8 = (size_t)8 << 14;

#pragma unroll 1
  for (int rep = 0; rep < 5; ++rep) {
    issue_tile(gaf, gbf, Abase, Bbase, wid, 0, fs8);
    issue_tile(gaf, gbf, Abase, Bbase, wid, 1, fs8);
    issue_tile(gaf, gbf, Abase, Bbase, wid, 2, fs8);
    asm volatile("s_waitcnt vmcnt(8)" ::: "memory");
    SB; BAR; SB;
#pragma unroll 1
    for (int t = 0; t < NKT - 3; ++t) {
      issue_tile(gaf, gbf, Abase, Bbase, wid, t + 3, fs8);
      asm volatile("s_waitcnt vmcnt(8)" ::: "memory");
      SB; BAR; SB;
    }
    asm volatile("s_waitcnt vmcnt(4)" ::: "memory");
    SB; BAR; SB;
    asm volatile("s_waitcnt vmcnt(0)" ::: "memory");
    SB; BAR; SB;
  }
  junk[(size_t)blockIdx.x * 512 + tid] = smem[tid];   // keep LDS live
}

// ---------------- PROBE B: ds_read+MFMA-only x5 (ablation) ----------------
// Deterministic LDS init, then the exact per-tile {12x ds_read_b128, 32 MFMA,
// barrier} loop with no staging. Dispatch duration / 5 = per-sweep compute cost.
__global__ __launch_bounds__(512, 2) void probe_mfma(signed char* __restrict__ junk) {
  extern __shared__ __align__(16) signed char smem[];
  signed char* Abase = smem;
  signed char* Bbase = smem + 65536;
  const int tid = threadIdx.x;
  const int lane = tid & 63;
  const int wid = tid >> 6;
  const int wr = wid >> 2;
  const int wc = wid & 3;

  // deterministic LDS fill: 512 threads x 256B
  uint4* p = (uint4*)smem;
#pragma unroll
  for (int i = 0; i < 16; ++i)
    p[tid * 16 + i] = make_uint4(tid * 7 + i, tid ^ (i * 73), i * 2654435761u, tid + i * 19);
  __syncthreads();

  i32x4 acc[8][4];
#pragma unroll
  for (int i = 0; i < 8; i++)
#pragma unroll
    for (int j = 0; j < 4; j++) acc[i][j] = (i32x4){0, 0, 0, 0};
  i32x4 af[8], bf[4];

#define RD_A(i_, mf_) af[i_] = *(const i32x4*)(Abase + (((buf_ * 16) + (mf_)) << 10) + lane * 16)
#define RD_B(j_, nf_) bf[j_] = *(const i32x4*)(Bbase + (((buf_ * 16) + (nf_)) << 10) + lane * 16)
#define MFMA16(IB)                                                             \
  do {                                                                         \
    __builtin_amdgcn_s_setprio(1);                                             \
    _Pragma("unroll") for (int i_ = 0; i_ < 4; i_++)                           \
      _Pragma("unroll") for (int j_ = 0; j_ < 4; j_++)                         \
        acc[(IB) + i_][j_] = __builtin_amdgcn_mfma_i32_16x16x64_i8(            \
            af[(IB) + i_], bf[j_], acc[(IB) + i_][j_], 0, 0, 0);               \
    __builtin_amdgcn_s_setprio(0);                                             \
  } while (0)

#pragma unroll 1
  for (int rep = 0; rep < 5; ++rep) {
#pragma unroll 1
    for (int t = 0; t < NKT; ++t) {
      const int buf_ = t & 3;
      RD_A(0, wr * 8 + 0); RD_A(1, wr * 8 + 1);
      RD_A(2, wr * 8 + 2); RD_A(3, wr * 8 + 3);
      RD_B(0, wc * 4 + 0); RD_B(1, wc * 4 + 1);
      RD_B(2, wc * 4 + 2); RD_B(3, wc * 4 + 3);
      RD_A(4, wr * 8 + 4); RD_A(5, wr * 8 + 5);
      RD_A(6, wr * 8 + 6); RD_A(7, wr * 8 + 7);
      MFMA16(0);
      MFMA16(4);
      SB; BAR; SB;
    }
  }
#undef MFMA16
#undef RD_A
#undef RD_B
  int s = 0;
#pragma unroll
  for (int i = 0; i < 8; i++)
#pragma unroll
    for (int j = 0; j < 4; j++)
      s += acc[i][j][0] + acc[i][j][1] + acc[i][j][2] + acc[i][j][3];
  ((int*)junk)[(size_t)blockIdx.x * 512 + tid] = s;   // deterministic checksum
}

// ---------------- 4) int8 GEMM (byte-identical schedule to R7) ----------------
__global__ __launch_bounds__(512, 2) void gemm_kernel(
    const signed char* __restrict__ A, const signed char* __restrict__ W,
    const float* __restrict__ bscale, const float* __restrict__ bint,
    float* __restrict__ out, int M, int N, int K) {
  extern __shared__ __align__(16) signed char smem[];   // 131072 B
  signed char* Abase = smem;
  signed char* Bbase = smem + 65536;

  const int nwg = gridDim.x;
  const int orig = blockIdx.x;
  const int wgid = (orig & 7) * (nwg >> 3) + (orig >> 3);
  const int nbn = N / BN;
  const int bm = wgid / nbn;
  const int bn = wgid % nbn;
  const int m0 = bm * BM, n0 = bn * BN;

  const int tid = threadIdx.x;
  const int lane = tid & 63;
  const int wid = tid >> 6;
  const int wr = wid >> 2;
  const int wc = wid & 3;

  const signed char* gaf = A + (((size_t)(m0 >> 4) + wid) << 14) + (lane << 4);
  const signed char* gbf = W + (((size_t)(n0 >> 4) + wid) << 14) + (lane << 4);
  const size_t fs8 = (size_t)8 << 14;

  i32x4 acc[8][4];
#pragma unroll
  for (int i = 0; i < 8; i++)
#pragma unroll
    for (int j = 0; j < 4; j++) acc[i][j] = (i32x4){0, 0, 0, 0};

  i32x4 af[8], bf[4];

#define RD_A(i_, mf_) af[i_] = *(const i32x4*)(Abase + (((buf_ * 16) + (mf_)) << 10) + lane * 16)
#define RD_B(j_, nf_) bf[j_] = *(const i32x4*)(Bbase + (((buf_ * 16) + (nf_)) << 10) + lane * 16)
#define MFMA16(IB)                                                             \
  do {                                                                         \
    __builtin_amdgcn_s_setprio(1);                                             \
    _Pragma("unroll") for (int i_ = 0; i_ < 4; i_++)                           \
      _Pragma("unroll") for (int j_ = 0; j_ < 4; j_++)                         \
        acc[(IB) + i_][j_] = __builtin_amdgcn_mfma_i32_16x16x64_i8(            \
            af[(IB) + i_], bf[j_], acc[(IB) + i_][j_], 0, 0, 0);               \
    __builtin_amdgcn_s_setprio(0);                                             \
  } while (0)
#define TILE(t, DO_ISSUE, VMW, DO_VM)                                          \
  do {                                                                         \
    const int buf_ = (t) & 3;                                                  \
    if (DO_ISSUE) issue_tile(gaf, gbf, Abase, Bbase, wid, (t) + 3, fs8);       \
    RD_A(0, wr * 8 + 0); RD_A(1, wr * 8 + 1);                                  \
    RD_A(2, wr * 8 + 2); RD_A(3, wr * 8 + 3);                                  \
    RD_B(0, wc * 4 + 0); RD_B(1, wc * 4 + 1);                                  \
    RD_B(2, wc * 4 + 2); RD_B(3, wc * 4 + 3);                                  \
    RD_A(4, wr * 8 + 4); RD_A(5, wr * 8 + 5);                                  \
    RD_A(6, wr * 8 + 6); RD_A(7, wr * 8 + 7);                                  \
    MFMA16(0);                                                                 \
    MFMA16(4);                                                                 \
    if (DO_VM) { asm volatile("s_waitcnt " VMW ::: "memory"); }                \
    SB; BAR; SB;                                                               \
  } while (0)

  issue_tile(gaf, gbf, Abase, Bbase, wid, 0, fs8);
  issue_tile(gaf, gbf, Abase, Bbase, wid, 1, fs8);
  issue_tile(gaf, gbf, Abase, Bbase, wid, 2, fs8);
  asm volatile("s_waitcnt vmcnt(8)" ::: "memory");
  SB; BAR; SB;

#pragma unroll 1
  for (int t = 0; t < NKT - 3; ++t) {
    TILE(t, 1, "vmcnt(8)", 1);
  }
  TILE(NKT - 3, 0, "vmcnt(4)", 1);
  TILE(NKT - 2, 0, "vmcnt(0)", 1);
  TILE(NKT - 1, 0, "", 0);
#undef TILE
#undef MFMA16
#undef RD_A
#undef RD_B

  // LDS-staged coalesced epilogue (unchanged from R5)
  float* Cst = (float*)smem;
  const int rr = (lane >> 4) * 4;
  const int cc = lane & 15;
#pragma unroll
  for (int h = 0; h < 2; ++h) {
    if (wr == h) {
#pragma unroll
      for (int j = 0; j < 4; j++) {
        const int colL = wc * 64 + j * 16 + cc;
        const float bs = bscale[n0 + colL];
        const float bi = bint[n0 + colL];
#pragma unroll
        for (int i = 0; i < 8; i++)
#pragma unroll
          for (int r = 0; r < 4; r++)
            Cst[(i * 16 + rr + r) * 256 + colL] = ((float)acc[i][j][r] + bi) * bs;
      }
    }
    WAIT_LGKM0;
    BAR;
    const size_t rowbase = (size_t)(m0 + h * 128) * N + n0;
#pragma unroll
    for (int it = 0; it < 16; ++it) {
      const int r_ = it * 8 + wid;
      float4 v = *(const float4*)&Cst[r_ * 256 + lane * 4];
      *(float4*)&out[rowbase + (size_t)r_ * N + lane * 4] = v;
    }
    WAIT_LGKM0;
    BAR;
  }
}

// ---------------- launch ----------------
extern "C" void kernel_launch(void* const* d_in, const int* in_sizes, int n_in,
                              void* d_out, int out_size, void* d_ws, size_t ws_size,
                              hipStream_t stream) {
  const float* hs = (const float*)d_in[0];
  const float* w = (const float*)d_in[1];
  const float* bias = (const float*)d_in[2];
  float* out = (float*)d_out;

  const long long n = (long long)in_sizes[0];     // 50331648
  const int K = K_DIM;                            // 1024
  const int O = in_sizes[2];                      // 1024
  const int M = (int)(n / K);                     // 49152

  // workspace layout
  char* ws = (char*)d_ws;
  unsigned int* amax_u = (unsigned int*)ws;                        // 4 B
  float* parts = (float*)(ws + 1024);                              // 8 KB
  float* bscale = (float*)(ws + 16384);                            // 4 KB
  float* bint = (float*)(ws + 20480);                              // 4 KB
  signed char* wq = (signed char*)(ws + 65536);                    // 1 MB (frag-ordered)
  signed char* xq = (signed char*)(ws + 65536 + 1048576);          // 48 MB (frag-ordered)
  signed char* junkA = (signed char*)(ws + ((size_t)64 << 20));    // probe scratch
  signed char* junkB = (signed char*)(ws + ((size_t)66 << 20));    // probe scratch

  hipFuncSetAttribute((const void*)gemm_kernel,
                      hipFuncAttributeMaxDynamicSharedMemorySize, 131072);
  hipFuncSetAttribute((const void*)probe_stage,
                      hipFuncAttributeMaxDynamicSharedMemorySize, 131072);
  hipFuncSetAttribute((const void*)probe_mfma,
                      hipFuncAttributeMaxDynamicSharedMemorySize, 131072);

  const long long n4 = n / 4;
  absmax_part<<<2048, 256, 0, stream>>>(hs, parts, n4);
  absmax_fin<<<1, 256, 0, stream>>>(parts, amax_u, 2048);
  wquant_kernel<<<O, 256, 0, stream>>>(w, bias, amax_u, wq, bscale, bint);
  const int nchunk = (int)(n / 16);
  aquant_kernel<<<2048, 256, 0, stream>>>(hs, amax_u, (uint4*)xq, nchunk);

  const int nblocks = (M / BM) * (O / BN);        // 768
  // ---- ablation probes (amplified x5; write junk scratch, then real GEMM) ----
  probe_stage<<<nblocks, 512, 131072, stream>>>(xq, wq, junkA, O);
  probe_mfma<<<nblocks, 512, 131072, stream>>>(junkB);
  gemm_kernel<<<nblocks, 512, 131072, stream>>>(xq, wq, bscale, bint, out, M, O, K);
}

// Round 9
// 180.229 us; speedup vs baseline: 2.3985x; 2.3985x over previous
//
#include <hip/hip_runtime.h>
#include <stdint.h>

typedef int i32x4 __attribute__((ext_vector_type(4)));

#define K_DIM 1024
#define BM 256
#define BN 256
#define BKK 64
#define NKT (K_DIM / BKK)   // 16

// Fragment-ordered int8 operand layout (producers aquant/wquant <-> consumer GEMM):
// fragment (F = row/16, T = k/64) is 1KB at offset ((F*16)+T)*1024; byte b
// (l=b>>4, j=b&15) holds value[row=F*16+(l&15)][k=T*64+(l>>4)*16+j].
// -> A gld_lds reads are 1KB contiguous; B fragments load STRAIGHT TO REGISTERS
//    (one b128/lane, perfectly coalesced) — no LDS round-trip for B at all.

// ---------------- helpers ----------------
__device__ __forceinline__ int quant1(float v, float inv) {
  float t = rintf(v * inv);                 // round half-to-even, matches jnp.round
  t = fminf(fmaxf(t, -128.0f), 127.0f);     // clip(-n-1, n)
  return (int)t;
}

__device__ __forceinline__ void gld_lds16(const signed char* g, signed char* l) {
  typedef const __attribute__((address_space(1))) unsigned int* gp_t;
  typedef __attribute__((address_space(3))) unsigned int* lp_t;
  __builtin_amdgcn_global_load_lds((gp_t)(const void*)g, (lp_t)(void*)l, 16, 0, 0);
}

#define SB __builtin_amdgcn_sched_barrier(0)
#define BAR __builtin_amdgcn_s_barrier()
#define WAIT_LGKM0 asm volatile("s_waitcnt lgkmcnt(0)" ::: "memory")

// ---------------- 1a) absmax partials ----------------
__global__ void absmax_part(const float* __restrict__ x, float* __restrict__ parts,
                            long long n4) {
  long long i = (long long)blockIdx.x * blockDim.x + threadIdx.x;
  const long long stride = (long long)gridDim.x * blockDim.x;
  const float4* x4 = (const float4*)x;
  float m = 0.0f;
  for (; i < n4; i += stride) {
    float4 v = x4[i];
    m = fmaxf(m, fmaxf(fmaxf(fabsf(v.x), fabsf(v.y)), fmaxf(fabsf(v.z), fabsf(v.w))));
  }
#pragma unroll
  for (int off = 32; off > 0; off >>= 1) m = fmaxf(m, __shfl_down(m, off, 64));
  __shared__ float sm[4];
  const int lane = threadIdx.x & 63, wid = threadIdx.x >> 6;
  if (lane == 0) sm[wid] = m;
  __syncthreads();
  if (threadIdx.x == 0)
    parts[blockIdx.x] = fmaxf(fmaxf(sm[0], sm[1]), fmaxf(sm[2], sm[3]));
}

// ---------------- 1b) absmax final reduce ----------------
__global__ void absmax_fin(const float* __restrict__ parts, unsigned int* __restrict__ amax_u,
                           int nparts) {
  const int t = threadIdx.x;
  float m = 0.0f;
  for (int i = t; i < nparts; i += 256) m = fmaxf(m, parts[i]);
#pragma unroll
  for (int off = 32; off > 0; off >>= 1) m = fmaxf(m, __shfl_down(m, off, 64));
  __shared__ float sm[4];
  const int lane = t & 63, wid = t >> 6;
  if (lane == 0) sm[wid] = m;
  __syncthreads();
  if (t == 0)
    amax_u[0] = __float_as_uint(fmaxf(fmaxf(sm[0], sm[1]), fmaxf(sm[2], sm[3])));
}

// ---------------- 2) per-channel weight quant + bias (frag-ordered wq) ----------------
__global__ void wquant_kernel(const float* __restrict__ w, const float* __restrict__ bias,
                              const unsigned int* __restrict__ amax_u,
                              signed char* __restrict__ wq,
                              float* __restrict__ bscale, float* __restrict__ bint) {
  const int o = blockIdx.x;
  const int t = threadIdx.x;          // handles k = 4t .. 4t+3
  float4 v = ((const float4*)(w + (size_t)o * K_DIM))[t];
  float m = fmaxf(fmaxf(fabsf(v.x), fabsf(v.y)), fmaxf(fabsf(v.z), fabsf(v.w)));
#pragma unroll
  for (int off = 32; off > 0; off >>= 1) m = fmaxf(m, __shfl_down(m, off, 64));
  __shared__ float sm[4];
  __shared__ float s_scale;
  const int lane = t & 63, wid = t >> 6;
  if (lane == 0) sm[wid] = m;
  __syncthreads();
  if (t == 0) {
    float wm = fmaxf(fmaxf(sm[0], sm[1]), fmaxf(sm[2], sm[3]));
    float wsc = fmaxf(wm, 1e-8f) / 127.0f;
    float asc = fmaxf(__uint_as_float(*amax_u), 1e-8f) / 127.0f;
    float bsc = wsc * asc;
    bscale[o] = bsc;
    bint[o] = rintf(bias[o] / bsc);
    s_scale = wsc;
  }
  __syncthreads();
  const float inv = 1.0f / s_scale;
  int q0 = quant1(v.x, inv), q1 = quant1(v.y, inv), q2 = quant1(v.z, inv), q3 = quant1(v.w, inv);
  unsigned int p = (unsigned)(q0 & 255) | ((unsigned)(q1 & 255) << 8) |
                   ((unsigned)(q2 & 255) << 16) | ((unsigned)(q3 & 255) << 24);
  const int F = o >> 4, T = t >> 4;
  const int l = (((t >> 2) & 3) << 4) | (o & 15);
  const int j = (t << 2) & 15;
  *(unsigned int*)(wq + (((size_t)F << 14) + (T << 10) + (l << 4) + j)) = p;
}

// ---------------- 3) activation quant (frag-ordered xq) ----------------
__global__ void aquant_kernel(const float* __restrict__ x, const unsigned int* __restrict__ amax_u,
                              uint4* __restrict__ q16, int nchunk) {
  const float asc = fmaxf(__uint_as_float(*amax_u), 1e-8f) / 127.0f;
  const float inv = 1.0f / asc;
  int c = blockIdx.x * blockDim.x + threadIdx.x;
  const int stride = gridDim.x * blockDim.x;
  for (; c < nchunk; c += stride) {
    const int l = c & 63, T = (c >> 6) & 15, F = c >> 10;
    const size_t src = (((size_t)(F << 4) + (l & 15)) << 10) + (T << 6) + ((l >> 4) << 4);
    const float4* s4 = (const float4*)(x + src);
    unsigned int r[4];
#pragma unroll
    for (int q = 0; q < 4; q++) {
      float4 v = s4[q];
      int q0 = quant1(v.x, inv), q1 = quant1(v.y, inv), q2 = quant1(v.z, inv), q3 = quant1(v.w, inv);
      r[q] = (unsigned)(q0 & 255) | ((unsigned)(q1 & 255) << 8) |
             ((unsigned)(q2 & 255) << 16) | ((unsigned)(q3 & 255) << 24);
    }
    q16[c] = make_uint4(r[0], r[1], r[2], r[3]);
  }
}

// ---------------- 4) int8 GEMM: A via LDS, B direct-to-registers ----------------
// Per K-tile per wave: 4 global b128 (B(t+1) -> spare reg set, L2-hit),
// 2 gld_lds (A(t+3)), 8 ds_read_b128 (A frags), 32 MFMA, counted vmcnt(8),
// ONE barrier. LDS = 4 A-buffers (64KB); B never touches LDS.
// 2-tile unrolled (full 16-tile unroll) so bf set selection is compile-time.
__global__ __launch_bounds__(512, 2) void gemm_kernel(
    const signed char* __restrict__ A, const signed char* __restrict__ W,
    const float* __restrict__ bscale, const float* __restrict__ bint,
    float* __restrict__ out, int M, int N, int K) {
  extern __shared__ __align__(16) signed char smem[];   // 65536 B: 4 x [16][1024] A bufs
  signed char* Abase = smem;

  // bijective XCD swizzle (gridDim.x % 8 == 0)
  const int nwg = gridDim.x;
  const int orig = blockIdx.x;
  const int wgid = (orig & 7) * (nwg >> 3) + (orig >> 3);
  const int nbn = N / BN;
  const int bm = wgid / nbn;
  const int bn = wgid % nbn;
  const int m0 = bm * BM, n0 = bn * BN;

  const int tid = threadIdx.x;
  const int lane = tid & 63;
  const int wid = tid >> 6;          // 8 waves
  const int wr = wid >> 1 >> 1;      // == wid >> 2, 2 wave-rows
  const int wc = wid & 3;            // 4 wave-cols

  // A: wave stages frags {wid, wid+8} of each K-tile
  const signed char* gaf = A + (((size_t)(m0 >> 4) + wid) << 14) + (lane << 4);
  const size_t fs8 = (size_t)8 << 14;
  // B: wave reads its 4 n-frags (wc*4+j) straight to regs; frag j at +j<<14
  const signed char* gbf = W + (((size_t)(n0 >> 4) + wc * 4) << 14) + (lane << 4);

  i32x4 acc[8][4];
#pragma unroll
  for (int i = 0; i < 8; i++)
#pragma unroll
    for (int j = 0; j < 4; j++) acc[i][j] = (i32x4){0, 0, 0, 0};

  i32x4 af[8];
  i32x4 bfA[4], bfB[4];

#define LOADB(L, tt)                                                           \
  do {                                                                         \
    L[0] = *(const i32x4*)(gbf + ((size_t)0 << 14) + ((tt) << 10));            \
    L[1] = *(const i32x4*)(gbf + ((size_t)1 << 14) + ((tt) << 10));            \
    L[2] = *(const i32x4*)(gbf + ((size_t)2 << 14) + ((tt) << 10));            \
    L[3] = *(const i32x4*)(gbf + ((size_t)3 << 14) + ((tt) << 10));            \
  } while (0)

#define ISSUEA(tt)                                                             \
  do {                                                                         \
    gld_lds16(gaf + ((size_t)(tt) << 10),                                      \
              Abase + ((((tt) & 3) * 16 + wid) << 10));                        \
    gld_lds16(gaf + fs8 + ((size_t)(tt) << 10),                                \
              Abase + ((((tt) & 3) * 16 + wid + 8) << 10));                    \
  } while (0)

#define RD_A(t, i_)                                                            \
  af[i_] = *(const i32x4*)(Abase + ((((t) & 3) * 16 + wr * 8 + (i_)) << 10) + (lane << 4))

#define MFMA16U(IB, U)                                                         \
  do {                                                                         \
    __builtin_amdgcn_s_setprio(1);                                             \
    _Pragma("unroll") for (int i_ = 0; i_ < 4; i_++)                           \
      _Pragma("unroll") for (int j_ = 0; j_ < 4; j_++)                         \
        acc[(IB) + i_][j_] = __builtin_amdgcn_mfma_i32_16x16x64_i8(            \
            af[(IB) + i_], U[j_], acc[(IB) + i_][j_], 0, 0, 0);                \
    __builtin_amdgcn_s_setprio(0);                                             \
  } while (0)

// One K-tile. U = reg set holding B(t); L = set to fill with B(t+1).
#define TILE(t, U, L, DOB, DOA, VMW, DOVM)                                     \
  do {                                                                         \
    if (DOB) LOADB(L, (t) + 1);                                                \
    if (DOA) ISSUEA((t) + 3);                                                  \
    SB;                                                                        \
    RD_A(t, 0); RD_A(t, 1); RD_A(t, 2); RD_A(t, 3);                            \
    RD_A(t, 4); RD_A(t, 5); RD_A(t, 6); RD_A(t, 7);                            \
    MFMA16U(0, U);                                                             \
    MFMA16U(4, U);                                                             \
    if (DOVM) { asm volatile("s_waitcnt " VMW ::: "memory"); }                 \
    SB; BAR; SB;                                                               \
  } while (0)

  // prologue: A(0..2) staged, B(0) -> bfA; drain once, barrier.
  ISSUEA(0); ISSUEA(1); ISSUEA(2);
  LOADB(bfA, 0);
  asm volatile("s_waitcnt vmcnt(0)" ::: "memory");
  SB; BAR; SB;

  // steady state: end-of-tile vmcnt(8) leaves {A(t+2)x2, B(t+1)x4, A(t+3)x2}
  // in flight and forces A(t+1) landed (FIFO). Never drains mid-loop.
  TILE(0,  bfA, bfB, 1, 1, "vmcnt(8)", 1);
  TILE(1,  bfB, bfA, 1, 1, "vmcnt(8)", 1);
  TILE(2,  bfA, bfB, 1, 1, "vmcnt(8)", 1);
  TILE(3,  bfB, bfA, 1, 1, "vmcnt(8)", 1);
  TILE(4,  bfA, bfB, 1, 1, "vmcnt(8)", 1);
  TILE(5,  bfB, bfA, 1, 1, "vmcnt(8)", 1);
  TILE(6,  bfA, bfB, 1, 1, "vmcnt(8)", 1);
  TILE(7,  bfB, bfA, 1, 1, "vmcnt(8)", 1);
  TILE(8,  bfA, bfB, 1, 1, "vmcnt(8)", 1);
  TILE(9,  bfB, bfA, 1, 1, "vmcnt(8)", 1);
  TILE(10, bfA, bfB, 1, 1, "vmcnt(8)", 1);
  TILE(11, bfB, bfA, 1, 1, "vmcnt(8)", 1);
  TILE(12, bfA, bfB, 1, 1, "vmcnt(8)", 1);
  TILE(13, bfB, bfA, 1, 0, "vmcnt(6)", 1);   // last A issued at t=12 (A15)
  TILE(14, bfA, bfB, 1, 0, "vmcnt(4)", 1);   // B(15) in flight
  TILE(15, bfB, bfA, 0, 0, "", 0);

#undef TILE
#undef MFMA16U
#undef RD_A
#undef ISSUEA
#undef LOADB

  // ---- epilogue: LDS-staged coalesced C writes, 4 quarters of 64 rows (64KB) ----
  float* Cst = (float*)smem;
  const int rr = (lane >> 4) * 4;
  const int cc = lane & 15;
#pragma unroll
  for (int q = 0; q < 4; ++q) {
    if (wr == (q >> 1)) {
#pragma unroll
      for (int j = 0; j < 4; j++) {
        const int colL = wc * 64 + j * 16 + cc;
        const float bs = bscale[n0 + colL];
        const float bi = bint[n0 + colL];
#pragma unroll
        for (int i2 = 0; i2 < 4; i2++) {
          const int i = (q & 1) * 4 + i2;
#pragma unroll
          for (int r = 0; r < 4; r++)
            Cst[(i2 * 16 + rr + r) * 256 + colL] = ((float)acc[i][j][r] + bi) * bs;
        }
      }
    }
    WAIT_LGKM0;
    BAR;
    const size_t rowbase = (size_t)(m0 + q * 64) * N + n0;
#pragma unroll
    for (int it = 0; it < 8; ++it) {
      const int r_ = it * 8 + wid;                  // 0..63
      float4 v = *(const float4*)&Cst[r_ * 256 + lane * 4];
      *(float4*)&out[rowbase + (size_t)r_ * N + lane * 4] = v;
    }
    WAIT_LGKM0;
    BAR;
  }
}

// ---------------- launch ----------------
extern "C" void kernel_launch(void* const* d_in, const int* in_sizes, int n_in,
                              void* d_out, int out_size, void* d_ws, size_t ws_size,
                              hipStream_t stream) {
  const float* hs = (const float*)d_in[0];
  const float* w = (const float*)d_in[1];
  const float* bias = (const float*)d_in[2];
  float* out = (float*)d_out;

  const long long n = (long long)in_sizes[0];     // 50331648
  const int K = K_DIM;                            // 1024
  const int O = in_sizes[2];                      // 1024
  const int M = (int)(n / K);                     // 49152

  // workspace layout
  char* ws = (char*)d_ws;
  unsigned int* amax_u = (unsigned int*)ws;                        // 4 B
  float* parts = (float*)(ws + 1024);                              // 8 KB
  float* bscale = (float*)(ws + 16384);                            // 4 KB
  float* bint = (float*)(ws + 20480);                              // 4 KB
  signed char* wq = (signed char*)(ws + 65536);                    // 1 MB (frag-ordered)
  signed char* xq = (signed char*)(ws + 65536 + 1048576);          // 48 MB (frag-ordered)

  hipFuncSetAttribute((const void*)gemm_kernel,
                      hipFuncAttributeMaxDynamicSharedMemorySize, 65536);

  const long long n4 = n / 4;
  absmax_part<<<2048, 256, 0, stream>>>(hs, parts, n4);
  absmax_fin<<<1, 256, 0, stream>>>(parts, amax_u, 2048);
  wquant_kernel<<<O, 256, 0, stream>>>(w, bias, amax_u, wq, bscale, bint);
  const int nchunk = (int)(n / 16);
  aquant_kernel<<<2048, 256, 0, stream>>>(hs, amax_u, (uint4*)xq, nchunk);

  const int nblocks = (M / BM) * (O / BN);        // 768
  gemm_kernel<<<nblocks, 512, 65536, stream>>>(xq, wq, bscale, bint, out, M, O, K);
}